// Round 11
// baseline (159.895 us; speedup 1.0000x reference)
//
#include <hip/hip_runtime.h>
#include <hip/hip_bf16.h>

#define N_NODES 100000
#define N_IN    64
#define N_OUT   64
#define N_EDGES 1600000

#define BSHIFT  7
#define NPB     128                              // nodes per bucket
#define NB      782                              // ceil(N_NODES / NPB)
#define CAP     2560                             // bucket cap: mean 2046 + ~11 sigma
#define CSTRIDE 16                               // cursor stride: 1 per 64B line
#define P1_EPT  16
#define P1_EPB  (512 * P1_EPT)                   // 8192 edges / block
#define P1_BLOCKS ((N_EDGES + P1_EPB - 1) / P1_EPB)  // 196
#define GEMM_BLOCKS ((N_NODES + 63) / 64)        // 1563

__device__ inline unsigned short f2bf(float f) {
    __hip_bfloat16 b = __float2bfloat16(f);
    union { __hip_bfloat16 b; unsigned short u; } c; c.b = b; return c.u;
}

// ---------------------------------------------------------------------------
// Fused prep (512 threads) — exact R7 config (best measured: 153.6 total).
// Blocks [0, P1_BLOCKS): bucket 8192 edges by dst>>7, single pass, LDS int
// histogram -> one global reservation per (block,bucket) -> run-grouped
// scattered writes. R11 change: bucket_cursor padded to 1 int per 64 B line
// (reservation atomics from 196 blocks previously hit 782 ints on 49 shared
// lines -> same-line serialization).
// Blocks [P1_BLOCKS, +GEMM_BLOCKS): h = X@W bf16, 64 rows/block, W in LDS.
// ---------------------------------------------------------------------------
__global__ __launch_bounds__(512) void prep_kernel(
        const float* __restrict__ X, const float* __restrict__ W,
        unsigned short* __restrict__ h,
        const int* __restrict__ edge_src, const int* __restrict__ edge_dst,
        const float* __restrict__ edge_val,
        int* __restrict__ bucket_cursor, int2* __restrict__ staged) {
    __shared__ float Ws[N_IN * N_OUT];   // 16 KB, dual-purpose
    const int t = threadIdx.x;

    if (blockIdx.x >= P1_BLOCKS) {
        // ---------------- GEMM tile: 64 rows x 64 cols ----------------
        const int blk = blockIdx.x - P1_BLOCKS;
        for (int i = t * 4; i < N_IN * N_OUT; i += 512 * 4)
            *(float4*)&Ws[i] = *(const float4*)&W[i];
        __syncthreads();

        const int r0 = blk * 64 + (t >> 4) * 2;
        const int c0 = (t & 15) * 4;
        if (r0 >= N_NODES) return;

        float acc0[4] = {0.f, 0.f, 0.f, 0.f};
        float acc1[4] = {0.f, 0.f, 0.f, 0.f};
        const float* x0p = X + (size_t)r0 * N_IN;
        const float* x1p = x0p + N_IN;

#pragma unroll 4
        for (int k4 = 0; k4 < 16; ++k4) {
            const float4 x0 = *(const float4*)(x0p + k4 * 4);
            const float4 x1 = *(const float4*)(x1p + k4 * 4);
            const float xa0[4] = {x0.x, x0.y, x0.z, x0.w};
            const float xa1[4] = {x1.x, x1.y, x1.z, x1.w};
#pragma unroll
            for (int kk = 0; kk < 4; ++kk) {
                const float4 w = *(const float4*)&Ws[(k4 * 4 + kk) * N_OUT + c0];
                acc0[0] = fmaf(xa0[kk], w.x, acc0[0]);
                acc0[1] = fmaf(xa0[kk], w.y, acc0[1]);
                acc0[2] = fmaf(xa0[kk], w.z, acc0[2]);
                acc0[3] = fmaf(xa0[kk], w.w, acc0[3]);
                acc1[0] = fmaf(xa1[kk], w.x, acc1[0]);
                acc1[1] = fmaf(xa1[kk], w.y, acc1[1]);
                acc1[2] = fmaf(xa1[kk], w.z, acc1[2]);
                acc1[3] = fmaf(xa1[kk], w.w, acc1[3]);
            }
        }
        ushort4 s0 = {f2bf(acc0[0]), f2bf(acc0[1]), f2bf(acc0[2]), f2bf(acc0[3])};
        ushort4 s1 = {f2bf(acc1[0]), f2bf(acc1[1]), f2bf(acc1[2]), f2bf(acc1[3])};
        *(ushort4*)&h[(size_t)r0 * N_OUT + c0] = s0;
        *(ushort4*)&h[(size_t)(r0 + 1) * N_OUT + c0] = s1;
    } else {
        // ---------------- bucket: 8192 edges by dst>>7 ----------------
        int* cnt  = (int*)Ws;          // NB ints
        int* base = cnt + NB;          // NB ints (6.3 KB total, fits in Ws)
        for (int i = t; i < NB; i += 512) cnt[i] = 0;
        __syncthreads();

        const int e0 = blockIdx.x * P1_EPB + t * P1_EPT;
        const bool act = (e0 + P1_EPT) <= N_EDGES;   // N_EDGES%16==0
        int bk[P1_EPT], pk[P1_EPT], vv[P1_EPT];

        if (act) {
#pragma unroll
            for (int q = 0; q < P1_EPT / 4; ++q) {
                const int4 d4 = *(const int4*)(edge_dst + e0 + q * 4);
                const int4 s4 = *(const int4*)(edge_src + e0 + q * 4);
                const int4 v4 = *(const int4*)((const int*)edge_val + e0 + q * 4);
                const int da[4] = {d4.x, d4.y, d4.z, d4.w};
                const int sa[4] = {s4.x, s4.y, s4.z, s4.w};
                const int va[4] = {v4.x, v4.y, v4.z, v4.w};
#pragma unroll
                for (int j = 0; j < 4; ++j) {
                    const int i = q * 4 + j;
                    const int d = da[j];
                    bk[i] = d >> BSHIFT;
                    pk[i] = sa[j] | ((d & (NPB - 1)) << 17);
                    vv[i] = va[j];
                    atomicAdd(&cnt[bk[i]], 1);
                }
            }
        }
        __syncthreads();
        for (int i = t; i < NB; i += 512) {
            const int c = cnt[i];
            base[i] = c ? atomicAdd(&bucket_cursor[i * CSTRIDE], c) : 0;
            cnt[i] = 0;  // reuse as intra-block cursor
        }
        __syncthreads();
        if (act) {
#pragma unroll
            for (int i = 0; i < P1_EPT; ++i) {
                const int b = bk[i];
                const int r = atomicAdd(&cnt[b], 1);
                const int pos = base[b] + r;
                if (pos < CAP) {
                    int2 o; o.x = pk[i]; o.y = vv[i];
                    staged[(size_t)b * CAP + pos] = o;
                }
            }
        }
    }
}

// ---------------------------------------------------------------------------
// Fused sort+gather: one 512-thread block per bucket — exact R7 form.
// Phase A: counting-sort into LDS, two strided streaming reads of the bucket
// (second is L2-hot). Int LDS atomics only (fp32 LDS atomicAdd = CAS loop,
// R4). No register-held edges (dynamic indexing spills — R9).
// Phase B: 8 waves x 16 nodes; quarter-wave per edge (h as uint2, 4 bf16
// feats/lane, 16 lanes/edge); 2-DEEP unroll — R7's best: with Poisson(16)
// degrees, 4-deep pushes the ~46% of runs below 16 edges into the serial
// remainder (R8-R10 regression); 2-deep keeps 2 loads in flight for any
// run >= 8 (84%). shfl_xor(16)+shfl_xor(32) reduce; fused ReLU; float4 store.
// ---------------------------------------------------------------------------
__global__ __launch_bounds__(512) void sort_gather_kernel(
        const uint2* __restrict__ h64,
        const int2* __restrict__ staged,
        const int* __restrict__ bucket_cursor,
        float* __restrict__ out) {
    __shared__ int2 srt[CAP];     // 20 KB sorted edges
    __shared__ int  ncnt[NPB];    // counts -> cursors -> run ends
    __shared__ int  noff[NPB];    // scan -> run starts
    const int t = threadIdx.x;
    const int b = blockIdx.x;
    const int cnt = min(bucket_cursor[b * CSTRIDE], CAP);
    const int2* bucket = staged + (size_t)b * CAP;

    if (t < NPB) ncnt[t] = 0;
    __syncthreads();
    for (int e = t; e < cnt; e += 512)
        atomicAdd(&ncnt[(unsigned)bucket[e].x >> 17], 1);
    __syncthreads();
    if (t < NPB) noff[t] = ncnt[t];
    __syncthreads();
    for (int d = 1; d < NPB; d <<= 1) {
        int x = 0;
        if (t < NPB && t >= d) x = noff[t - d];
        __syncthreads();
        if (t < NPB) noff[t] += x;
        __syncthreads();
    }
    if (t < NPB) {
        const int excl = noff[t] - ncnt[t];
        noff[t] = excl;      // static run start
        ncnt[t] = excl;      // moving cursor (becomes run end)
    }
    __syncthreads();
    for (int e = t; e < cnt; e += 512) {
        const int2 p = bucket[e];
        const int node = (unsigned)p.x >> 17;
        const int pos = atomicAdd(&ncnt[node], 1);
        int2 o; o.x = p.x & 0x1FFFF; o.y = p.y;
        srt[pos] = o;
    }
    __syncthreads();

    const int w  = t >> 6;         // wave 0..7
    const int q  = (t >> 4) & 3;   // quarter 0..3 (edge slot)
    const int ql = t & 15;         // lane in quarter; feats 4*ql..4*ql+3

#define EDGE4(hw, v)                                                        \
    do {                                                                    \
        a0 = fmaf(__uint_as_float((hw).x << 16), (v), a0);                  \
        a1 = fmaf(__uint_as_float((hw).x & 0xffff0000u), (v), a1);          \
        a2 = fmaf(__uint_as_float((hw).y << 16), (v), a2);                  \
        a3 = fmaf(__uint_as_float((hw).y & 0xffff0000u), (v), a3);          \
    } while (0)

    for (int nl = w * 16; nl < w * 16 + 16; ++nl) {
        const int node = b * NPB + nl;
        if (node >= N_NODES) break;
        const int s = noff[nl];
        const int e_end = ncnt[nl];

        float a0 = 0.f, a1 = 0.f, a2 = 0.f, a3 = 0.f;
        int e = s + q;
        for (; e + 4 < e_end; e += 8) {          // 8 edges / wave iter, 2 loads in flight
            const int2 p0 = srt[e];
            const int2 p1 = srt[e + 4];
            const uint2 w0 = h64[(size_t)p0.x * 16 + ql];
            const uint2 w1 = h64[(size_t)p1.x * 16 + ql];
            const float v0 = __int_as_float(p0.y);
            const float v1 = __int_as_float(p1.y);
            EDGE4(w0, v0);
            EDGE4(w1, v1);
        }
        for (; e < e_end; e += 4) {
            const int2 p = srt[e];
            const uint2 w0 = h64[(size_t)p.x * 16 + ql];
            const float v = __int_as_float(p.y);
            EDGE4(w0, v);
        }
        a0 += __shfl_xor(a0, 16, 64); a0 += __shfl_xor(a0, 32, 64);
        a1 += __shfl_xor(a1, 16, 64); a1 += __shfl_xor(a1, 32, 64);
        a2 += __shfl_xor(a2, 16, 64); a2 += __shfl_xor(a2, 32, 64);
        a3 += __shfl_xor(a3, 16, 64); a3 += __shfl_xor(a3, 32, 64);
        if (q == 0) {
            float4 o;
            o.x = fmaxf(a0, 0.f);
            o.y = fmaxf(a1, 0.f);
            o.z = fmaxf(a2, 0.f);
            o.w = fmaxf(a3, 0.f);
            *(float4*)&out[(size_t)node * 64 + 4 * ql] = o;
        }
    }
#undef EDGE4
}

// ---------------------------------------------------------------------------
// Fallback path (ws too small): fp32 gemm + global atomic scatter + relu.
// ---------------------------------------------------------------------------
__global__ __launch_bounds__(256) void gemm_f32_kernel(const float* __restrict__ X,
                                                       const float* __restrict__ W,
                                                       float* __restrict__ h) {
    __shared__ float Ws[N_IN * N_OUT];
    for (int i = threadIdx.x * 4; i < N_IN * N_OUT; i += 256 * 4)
        *(float4*)&Ws[i] = *(const float4*)&W[i];
    __syncthreads();
    const int lane = threadIdx.x & 63;
    const int wid = threadIdx.x >> 6;
    for (int row = blockIdx.x * 4 + wid; row < N_NODES; row += gridDim.x * 4) {
        const float x = X[row * N_IN + lane];
        float acc = 0.0f;
#pragma unroll
        for (int k = 0; k < N_IN; ++k)
            acc = fmaf(__shfl(x, k), Ws[k * N_OUT + lane], acc);
        h[row * N_OUT + lane] = acc;
    }
}

__global__ __launch_bounds__(256) void scatter_kernel(const float* __restrict__ h,
                                                      const float* __restrict__ edge_val,
                                                      const int* __restrict__ edge_src,
                                                      const int* __restrict__ edge_dst,
                                                      float* __restrict__ out) {
    const int lane = threadIdx.x & 63;
    const int e = (int)((blockIdx.x * 256u + threadIdx.x) >> 6);
    if (e >= N_EDGES) return;
    const float m = h[(size_t)edge_src[e] * N_OUT + lane] * edge_val[e];
    atomicAdd(&out[(size_t)edge_dst[e] * N_OUT + lane], m);
}

__global__ __launch_bounds__(256) void relu_kernel(float* __restrict__ out, int n) {
    const int i = (int)(blockIdx.x * 256u + threadIdx.x) * 4;
    if (i + 3 < n) {
        float4 v = *(float4*)&out[i];
        v.x = fmaxf(v.x, 0.f); v.y = fmaxf(v.y, 0.f);
        v.z = fmaxf(v.z, 0.f); v.w = fmaxf(v.w, 0.f);
        *(float4*)&out[i] = v;
    }
}

extern "C" void kernel_launch(void* const* d_in, const int* in_sizes, int n_in,
                              void* d_out, int out_size, void* d_ws, size_t ws_size,
                              hipStream_t stream) {
    const float* X        = (const float*)d_in[0];
    const float* W        = (const float*)d_in[1];
    const float* edge_val = (const float*)d_in[2];
    const int*   edge_src = (const int*)d_in[3];
    const int*   edge_dst = (const int*)d_in[4];
    float*       out      = (float*)d_out;

    // ws layout: h(bf16) 12.8MB | staged 16.0MB | bucket_cursor 50KB (padded)
    unsigned short* h   = (unsigned short*)d_ws;
    int2* staged        = (int2*)((char*)d_ws + (size_t)N_NODES * N_OUT * 2);
    int*  bucket_cursor = (int*)(staged + (size_t)NB * CAP);
    const size_t need = (size_t)((char*)(bucket_cursor + NB * CSTRIDE) - (char*)d_ws);

    if (ws_size >= need) {
        hipMemsetAsync(bucket_cursor, 0, NB * CSTRIDE * sizeof(int), stream);
        prep_kernel<<<P1_BLOCKS + GEMM_BLOCKS, 512, 0, stream>>>(
            X, W, h, edge_src, edge_dst, edge_val, bucket_cursor, staged);
        sort_gather_kernel<<<NB, 512, 0, stream>>>((const uint2*)h, staged,
                                                   bucket_cursor, out);
    } else {
        float* hf = (float*)d_ws;  // 25.6 MB
        hipMemsetAsync(d_out, 0, (size_t)out_size * sizeof(float), stream);
        gemm_f32_kernel<<<25000, 256, 0, stream>>>(X, W, hf);
        const long long st = (long long)N_EDGES * 64;
        scatter_kernel<<<(int)((st + 255) / 256), 256, 0, stream>>>(
            hf, edge_val, edge_src, edge_dst, out);
        relu_kernel<<<(out_size / 4 + 255) / 256, 256, 0, stream>>>(out, out_size);
    }
}

// Round 12
// 154.723 us; speedup vs baseline: 1.0334x; 1.0334x over previous
//
#include <hip/hip_runtime.h>
#include <hip/hip_bf16.h>

#define N_NODES 100000
#define N_IN    64
#define N_OUT   64
#define N_EDGES 1600000

#define BSHIFT  7
#define NPB     128                              // nodes per bucket
#define NB      782                              // ceil(N_NODES / NPB)
#define CAP     2560                             // bucket cap: mean 2046 + ~11 sigma
#define CSTRIDE 16                               // cursor stride: 1 per 64B line
#define P1_EPT  16
#define P1_EPB  (512 * P1_EPT)                   // 8192 edges / block
#define P1_BLOCKS ((N_EDGES + P1_EPB - 1) / P1_EPB)  // 196
#define GEMM_BLOCKS ((N_NODES + 63) / 64)        // 1563

__device__ inline unsigned short f2bf(float f) {
    __hip_bfloat16 b = __float2bfloat16(f);
    union { __hip_bfloat16 b; unsigned short u; } c; c.b = b; return c.u;
}

// ---------------------------------------------------------------------------
// Fused prep (512 threads) — R7 config (best measured).
// Blocks [0, P1_BLOCKS): bucket 8192 edges by dst>>7, single pass, LDS int
// histogram -> one global reservation per (block,bucket) -> run-grouped
// scattered writes. Blocks [P1_BLOCKS, +GEMM_BLOCKS): h = X@W bf16,
// 64 rows/block, W in LDS as float4.
// ---------------------------------------------------------------------------
__global__ __launch_bounds__(512) void prep_kernel(
        const float* __restrict__ X, const float* __restrict__ W,
        unsigned short* __restrict__ h,
        const int* __restrict__ edge_src, const int* __restrict__ edge_dst,
        const float* __restrict__ edge_val,
        int* __restrict__ bucket_cursor, int2* __restrict__ staged) {
    __shared__ float Ws[N_IN * N_OUT];   // 16 KB, dual-purpose
    const int t = threadIdx.x;

    if (blockIdx.x >= P1_BLOCKS) {
        // ---------------- GEMM tile: 64 rows x 64 cols ----------------
        const int blk = blockIdx.x - P1_BLOCKS;
        for (int i = t * 4; i < N_IN * N_OUT; i += 512 * 4)
            *(float4*)&Ws[i] = *(const float4*)&W[i];
        __syncthreads();

        const int r0 = blk * 64 + (t >> 4) * 2;
        const int c0 = (t & 15) * 4;
        if (r0 >= N_NODES) return;

        float acc0[4] = {0.f, 0.f, 0.f, 0.f};
        float acc1[4] = {0.f, 0.f, 0.f, 0.f};
        const float* x0p = X + (size_t)r0 * N_IN;
        const float* x1p = x0p + N_IN;

#pragma unroll 4
        for (int k4 = 0; k4 < 16; ++k4) {
            const float4 x0 = *(const float4*)(x0p + k4 * 4);
            const float4 x1 = *(const float4*)(x1p + k4 * 4);
            const float xa0[4] = {x0.x, x0.y, x0.z, x0.w};
            const float xa1[4] = {x1.x, x1.y, x1.z, x1.w};
#pragma unroll
            for (int kk = 0; kk < 4; ++kk) {
                const float4 w = *(const float4*)&Ws[(k4 * 4 + kk) * N_OUT + c0];
                acc0[0] = fmaf(xa0[kk], w.x, acc0[0]);
                acc0[1] = fmaf(xa0[kk], w.y, acc0[1]);
                acc0[2] = fmaf(xa0[kk], w.z, acc0[2]);
                acc0[3] = fmaf(xa0[kk], w.w, acc0[3]);
                acc1[0] = fmaf(xa1[kk], w.x, acc1[0]);
                acc1[1] = fmaf(xa1[kk], w.y, acc1[1]);
                acc1[2] = fmaf(xa1[kk], w.z, acc1[2]);
                acc1[3] = fmaf(xa1[kk], w.w, acc1[3]);
            }
        }
        ushort4 s0 = {f2bf(acc0[0]), f2bf(acc0[1]), f2bf(acc0[2]), f2bf(acc0[3])};
        ushort4 s1 = {f2bf(acc1[0]), f2bf(acc1[1]), f2bf(acc1[2]), f2bf(acc1[3])};
        *(ushort4*)&h[(size_t)r0 * N_OUT + c0] = s0;
        *(ushort4*)&h[(size_t)(r0 + 1) * N_OUT + c0] = s1;
    } else {
        // ---------------- bucket: 8192 edges by dst>>7 ----------------
        int* cnt  = (int*)Ws;          // NB ints
        int* base = cnt + NB;          // NB ints (6.3 KB total, fits in Ws)
        for (int i = t; i < NB; i += 512) cnt[i] = 0;
        __syncthreads();

        const int e0 = blockIdx.x * P1_EPB + t * P1_EPT;
        const bool act = (e0 + P1_EPT) <= N_EDGES;   // N_EDGES%16==0
        int bk[P1_EPT], pk[P1_EPT], vv[P1_EPT];

        if (act) {
#pragma unroll
            for (int q = 0; q < P1_EPT / 4; ++q) {
                const int4 d4 = *(const int4*)(edge_dst + e0 + q * 4);
                const int4 s4 = *(const int4*)(edge_src + e0 + q * 4);
                const int4 v4 = *(const int4*)((const int*)edge_val + e0 + q * 4);
                const int da[4] = {d4.x, d4.y, d4.z, d4.w};
                const int sa[4] = {s4.x, s4.y, s4.z, s4.w};
                const int va[4] = {v4.x, v4.y, v4.z, v4.w};
#pragma unroll
                for (int j = 0; j < 4; ++j) {
                    const int i = q * 4 + j;
                    const int d = da[j];
                    bk[i] = d >> BSHIFT;
                    pk[i] = sa[j] | ((d & (NPB - 1)) << 17);
                    vv[i] = va[j];
                    atomicAdd(&cnt[bk[i]], 1);
                }
            }
        }
        __syncthreads();
        for (int i = t; i < NB; i += 512) {
            const int c = cnt[i];
            base[i] = c ? atomicAdd(&bucket_cursor[i * CSTRIDE], c) : 0;
            cnt[i] = 0;  // reuse as intra-block cursor
        }
        __syncthreads();
        if (act) {
#pragma unroll
            for (int i = 0; i < P1_EPT; ++i) {
                const int b = bk[i];
                const int r = atomicAdd(&cnt[b], 1);
                const int pos = base[b] + r;
                if (pos < CAP) {
                    int2 o; o.x = pk[i]; o.y = vv[i];
                    staged[(size_t)b * CAP + pos] = o;
                }
            }
        }
    }
}

// ---------------------------------------------------------------------------
// Fused sort+gather: one 512-thread block per bucket.
// Phase A (R7 streaming form): counting-sort into LDS, two strided global
// reads (second L2-hot). Int LDS atomics only (fp32 LDS atomicAdd = CAS
// loop, R4; register-held edges spill via dynamic indexing, R9).
// Phase B (R12): 8 lanes/edge, 2 NODES PER WAVE. Lane = n*32 + s*8 + l:
// n = node half, s = edge slot (4/node), l = feature octet. One uint4
// wave-load serves 8 edges (2x fewer vmem instrs than R7's 4); pairing two
// independent Poisson(16) runs per wave overlaps one run's short tail with
// the other's work (the R8-R10 deep-unroll failure, fixed structurally).
// 2-deep unroll = 8 loads in flight/wave. shfl_xor(8,16) reduce within
// half-wave; fused ReLU; 2x float4 store per s=0 lane.
// ---------------------------------------------------------------------------
__global__ __launch_bounds__(512) void sort_gather_kernel(
        const uint4* __restrict__ h128,
        const int2* __restrict__ staged,
        const int* __restrict__ bucket_cursor,
        float* __restrict__ out) {
    __shared__ int2 srt[CAP];     // 20 KB sorted edges
    __shared__ int  ncnt[NPB];    // counts -> cursors -> run ends
    __shared__ int  noff[NPB];    // scan -> run starts
    const int t = threadIdx.x;
    const int b = blockIdx.x;
    const int cnt = min(bucket_cursor[b * CSTRIDE], CAP);
    const int2* bucket = staged + (size_t)b * CAP;

    if (t < NPB) ncnt[t] = 0;
    __syncthreads();
    for (int e = t; e < cnt; e += 512)
        atomicAdd(&ncnt[(unsigned)bucket[e].x >> 17], 1);
    __syncthreads();
    if (t < NPB) noff[t] = ncnt[t];
    __syncthreads();
    for (int d = 1; d < NPB; d <<= 1) {
        int x = 0;
        if (t < NPB && t >= d) x = noff[t - d];
        __syncthreads();
        if (t < NPB) noff[t] += x;
        __syncthreads();
    }
    if (t < NPB) {
        const int excl = noff[t] - ncnt[t];
        noff[t] = excl;      // static run start
        ncnt[t] = excl;      // moving cursor (becomes run end)
    }
    __syncthreads();
    for (int e = t; e < cnt; e += 512) {
        const int2 p = bucket[e];
        const int node = (unsigned)p.x >> 17;
        const int pos = atomicAdd(&ncnt[node], 1);
        int2 o; o.x = p.x & 0x1FFFF; o.y = p.y;
        srt[pos] = o;
    }
    __syncthreads();

    const int w = t >> 6;          // wave 0..7
    const int n = (t >> 5) & 1;    // node half within wave
    const int s = (t >> 3) & 3;    // edge slot 0..3
    const int l = t & 7;           // feature octet: feats 8l..8l+7

#define BFLO(u) __uint_as_float((u) << 16)
#define BFHI(u) __uint_as_float((u) & 0xffff0000u)
#define EDGE8(hw, v)                                                        \
    do {                                                                    \
        a0 = fmaf(BFLO((hw).x), (v), a0); a1 = fmaf(BFHI((hw).x), (v), a1); \
        a2 = fmaf(BFLO((hw).y), (v), a2); a3 = fmaf(BFHI((hw).y), (v), a3); \
        a4 = fmaf(BFLO((hw).z), (v), a4); a5 = fmaf(BFHI((hw).z), (v), a5); \
        a6 = fmaf(BFLO((hw).w), (v), a6); a7 = fmaf(BFHI((hw).w), (v), a7); \
    } while (0)

#pragma unroll 1
    for (int pp = 0; pp < NPB / 16; ++pp) {      // 8 passes x 16 nodes
        const int nl = pp * 16 + w * 2 + n;
        const int node = b * NPB + nl;
        const int st  = noff[nl];
        const int e_end = ncnt[nl];              // == st for nodes >= N_NODES

        float a0 = 0.f, a1 = 0.f, a2 = 0.f, a3 = 0.f;
        float a4 = 0.f, a5 = 0.f, a6 = 0.f, a7 = 0.f;
        int e = st + s;
        for (; e + 4 < e_end; e += 8) {          // 8 edges / node-half iter
            const int2 p0 = srt[e];
            const int2 p1 = srt[e + 4];
            const uint4 w0 = h128[(size_t)p0.x * 8 + l];
            const uint4 w1 = h128[(size_t)p1.x * 8 + l];
            const float v0 = __int_as_float(p0.y);
            const float v1 = __int_as_float(p1.y);
            EDGE8(w0, v0);
            EDGE8(w1, v1);
        }
        for (; e < e_end; e += 4) {
            const int2 p = srt[e];
            const uint4 w0 = h128[(size_t)p.x * 8 + l];
            const float v = __int_as_float(p.y);
            EDGE8(w0, v);
        }
        a0 += __shfl_xor(a0, 8, 64);  a0 += __shfl_xor(a0, 16, 64);
        a1 += __shfl_xor(a1, 8, 64);  a1 += __shfl_xor(a1, 16, 64);
        a2 += __shfl_xor(a2, 8, 64);  a2 += __shfl_xor(a2, 16, 64);
        a3 += __shfl_xor(a3, 8, 64);  a3 += __shfl_xor(a3, 16, 64);
        a4 += __shfl_xor(a4, 8, 64);  a4 += __shfl_xor(a4, 16, 64);
        a5 += __shfl_xor(a5, 8, 64);  a5 += __shfl_xor(a5, 16, 64);
        a6 += __shfl_xor(a6, 8, 64);  a6 += __shfl_xor(a6, 16, 64);
        a7 += __shfl_xor(a7, 8, 64);  a7 += __shfl_xor(a7, 16, 64);
        if (s == 0 && node < N_NODES) {
            float4 o0, o1;
            o0.x = fmaxf(a0, 0.f); o0.y = fmaxf(a1, 0.f);
            o0.z = fmaxf(a2, 0.f); o0.w = fmaxf(a3, 0.f);
            o1.x = fmaxf(a4, 0.f); o1.y = fmaxf(a5, 0.f);
            o1.z = fmaxf(a6, 0.f); o1.w = fmaxf(a7, 0.f);
            *(float4*)&out[(size_t)node * 64 + 8 * l] = o0;
            *(float4*)&out[(size_t)node * 64 + 8 * l + 4] = o1;
        }
    }
#undef EDGE8
#undef BFLO
#undef BFHI
}

// ---------------------------------------------------------------------------
// Fallback path (ws too small): fp32 gemm + global atomic scatter + relu.
// ---------------------------------------------------------------------------
__global__ __launch_bounds__(256) void gemm_f32_kernel(const float* __restrict__ X,
                                                       const float* __restrict__ W,
                                                       float* __restrict__ h) {
    __shared__ float Ws[N_IN * N_OUT];
    for (int i = threadIdx.x * 4; i < N_IN * N_OUT; i += 256 * 4)
        *(float4*)&Ws[i] = *(const float4*)&W[i];
    __syncthreads();
    const int lane = threadIdx.x & 63;
    const int wid = threadIdx.x >> 6;
    for (int row = blockIdx.x * 4 + wid; row < N_NODES; row += gridDim.x * 4) {
        const float x = X[row * N_IN + lane];
        float acc = 0.0f;
#pragma unroll
        for (int k = 0; k < N_IN; ++k)
            acc = fmaf(__shfl(x, k), Ws[k * N_OUT + lane], acc);
        h[row * N_OUT + lane] = acc;
    }
}

__global__ __launch_bounds__(256) void scatter_kernel(const float* __restrict__ h,
                                                      const float* __restrict__ edge_val,
                                                      const int* __restrict__ edge_src,
                                                      const int* __restrict__ edge_dst,
                                                      float* __restrict__ out) {
    const int lane = threadIdx.x & 63;
    const int e = (int)((blockIdx.x * 256u + threadIdx.x) >> 6);
    if (e >= N_EDGES) return;
    const float m = h[(size_t)edge_src[e] * N_OUT + lane] * edge_val[e];
    atomicAdd(&out[(size_t)edge_dst[e] * N_OUT + lane], m);
}

__global__ __launch_bounds__(256) void relu_kernel(float* __restrict__ out, int n) {
    const int i = (int)(blockIdx.x * 256u + threadIdx.x) * 4;
    if (i + 3 < n) {
        float4 v = *(float4*)&out[i];
        v.x = fmaxf(v.x, 0.f); v.y = fmaxf(v.y, 0.f);
        v.z = fmaxf(v.z, 0.f); v.w = fmaxf(v.w, 0.f);
        *(float4*)&out[i] = v;
    }
}

extern "C" void kernel_launch(void* const* d_in, const int* in_sizes, int n_in,
                              void* d_out, int out_size, void* d_ws, size_t ws_size,
                              hipStream_t stream) {
    const float* X        = (const float*)d_in[0];
    const float* W        = (const float*)d_in[1];
    const float* edge_val = (const float*)d_in[2];
    const int*   edge_src = (const int*)d_in[3];
    const int*   edge_dst = (const int*)d_in[4];
    float*       out      = (float*)d_out;

    // ws layout: h(bf16) 12.8MB | staged 16.0MB | bucket_cursor 50KB (padded)
    unsigned short* h   = (unsigned short*)d_ws;
    int2* staged        = (int2*)((char*)d_ws + (size_t)N_NODES * N_OUT * 2);
    int*  bucket_cursor = (int*)(staged + (size_t)NB * CAP);
    const size_t need = (size_t)((char*)(bucket_cursor + NB * CSTRIDE) - (char*)d_ws);

    if (ws_size >= need) {
        hipMemsetAsync(bucket_cursor, 0, NB * CSTRIDE * sizeof(int), stream);
        prep_kernel<<<P1_BLOCKS + GEMM_BLOCKS, 512, 0, stream>>>(
            X, W, h, edge_src, edge_dst, edge_val, bucket_cursor, staged);
        sort_gather_kernel<<<NB, 512, 0, stream>>>((const uint4*)h, staged,
                                                   bucket_cursor, out);
    } else {
        float* hf = (float*)d_ws;  // 25.6 MB
        hipMemsetAsync(d_out, 0, (size_t)out_size * sizeof(float), stream);
        gemm_f32_kernel<<<25000, 256, 0, stream>>>(X, W, hf);
        const long long st = (long long)N_EDGES * 64;
        scatter_kernel<<<(int)((st + 255) / 256), 256, 0, stream>>>(
            hf, edge_val, edge_src, edge_dst, out);
        relu_kernel<<<(out_size / 4 + 255) / 256, 256, 0, stream>>>(out, out_size);
    }
}